// Round 2
// baseline (1158.891 us; speedup 1.0000x reference)
//
#include <hip/hip_runtime.h>
#include <hip/hip_bf16.h>
#include <stdint.h>

typedef __attribute__((ext_vector_type(8))) short short8;
typedef __attribute__((ext_vector_type(4))) float f32x4;

#define T_STEPS 10
#define BT 32
#define WPACK_BYTES (2048*1024)   // 2048 chunks x 1 KiB

__device__ __forceinline__ unsigned int pk2(float x, float y){
  unsigned int bx = __float_as_uint(x), by = __float_as_uint(y);
  bx = (bx + 0x7FFFu + ((bx>>16)&1u)) >> 16;     // RNE fp32->bf16
  by = (by + 0x7FFFu + ((by>>16)&1u)) >> 16;
  return bx | (by<<16);
}
__device__ __forceinline__ float sigf(float x){ return 1.f/(1.f + __expf(-x)); }
__device__ __forceinline__ float tanh_(float x){
  x = fminf(fmaxf(x, -15.f), 15.f);
  float e = __expf(2.f*x);
  return (e - 1.f)/(e + 1.f);
}

// ---- K0a: pack W_hh [2048][512] fp32 -> bf16, per-wave-contiguous order ----
// chunk = ((w*16 + kc)*4 + n)*4 + g   (w=jt>>2, n=jt&3, jt=j>>4)
// within chunk: lane = khi*16 + jl (khi=(k>>3)&3, jl=j&15), 8 shorts per lane
__global__ __launch_bounds__(256) void k_pack(const float* __restrict__ Whh,
                                              unsigned short* __restrict__ wp){
  int id  = blockIdx.x*256 + threadIdx.x;   // 0..131071
  int row = id >> 6;                        // gate col 0..2047
  int ko  = (id & 63) * 8;                  // k offset 0..504
  const float* p = Whh + row*512 + ko;
  float4 a = *(const float4*)p, b = *(const float4*)(p+4);
  uint4 v;
  v.x = pk2(a.x,a.y); v.y = pk2(a.z,a.w);
  v.z = pk2(b.x,b.y); v.w = pk2(b.z,b.w);
  int g = row >> 9, jin = row & 511, jt = jin >> 4, jl = jin & 15;
  int w = jt >> 2, n = jt & 3;
  int kc = ko >> 5, khi = (ko >> 3) & 3, lane = khi*16 + jl;
  int chunk = ((w*16 + kc)*4 + n)*4 + g;
  *(uint4*)(wp + chunk*512 + lane*8) = v;
}

// ---- K0b: v[j] = sum_h fc2[h]*fc1[h][j]; bias0 = fc2.fc1_b + fc2_b --------
__global__ __launch_bounds__(256) void k_v(const float* __restrict__ fc1w,
                                           const float* __restrict__ fc1b,
                                           const float* __restrict__ fc2w,
                                           const float* __restrict__ fc2b,
                                           float* __restrict__ vout,
                                           float* __restrict__ bias0){
  __shared__ float red[4][64];
  int tid = threadIdx.x;
  if (blockIdx.x < 16){
    int j  = blockIdx.x*64 + (tid & 63);
    int hc = tid >> 6;
    float s = 0.f;
    for (int hh = hc*128; hh < hc*128 + 128; ++hh)
      s += fc2w[hh] * fc1w[hh*1024 + j];
    red[hc][tid & 63] = s;
    __syncthreads();
    if (tid < 64)
      vout[blockIdx.x*64 + tid] = red[0][tid]+red[1][tid]+red[2][tid]+red[3][tid];
  } else {
    if (tid < 64){
      float s = 0.f;
      for (int i = 0; i < 8; ++i){ int hh = i*64 + tid; s += fc2w[hh]*fc1b[hh]; }
      for (int m = 32; m; m >>= 1) s += __shfl_xor(s, m);
      if (tid == 0) *bias0 = s + fc2b[0];
    }
  }
}

// ---- K2: out[b] = h[b,9,:].v2 + bias0 (overwrites -> deterministic init) --
__global__ __launch_bounds__(512) void k_init(const float* __restrict__ h,
                                              const float* __restrict__ v,
                                              const float* __restrict__ bias0,
                                              float* __restrict__ out){
  int w = threadIdx.x >> 6, lane = threadIdx.x & 63;
  float b0v = *bias0;
  const float* v2 = v + 512;
  for (int r = 0; r < 8; ++r){
    int b = blockIdx.x*64 + w*8 + r;
    const float* hp = h + ((size_t)b*T_STEPS + 9)*512 + lane*8;
    float4 x0 = *(const float4*)hp, x1 = *(const float4*)(hp+4);
    const float* vp = v2 + lane*8;
    float4 w0 = *(const float4*)vp, w1 = *(const float4*)(vp+4);
    float s = x0.x*w0.x + x0.y*w0.y + x0.z*w0.z + x0.w*w0.w
            + x1.x*w1.x + x1.y*w1.y + x1.z*w1.z + x1.w*w1.w;
    for (int m = 32; m; m >>= 1) s += __shfl_xor(s, m);
    if (lane == 0) out[b] = s + b0v;
  }
}

// ---- K1: GEMM pass over kc with explicit B double-buffer prefetch ----------
template<int NG, int N0>
__device__ __forceinline__ void gemm_pass(
    const unsigned short* As, const short8* __restrict__ wbase8,
    int llo, int lhi, f32x4 (&acc)[2][NG][2])
{
  short8 b[2][NG][2];
#pragma unroll
  for (int g=0; g<NG; ++g)
#pragma unroll
    for (int nn=0; nn<2; ++nn)
      b[0][g][nn] = wbase8[(((0*4) + (N0+nn))*4 + g)*64];

  int sw = (llo & 7) << 3;
#pragma unroll
  for (int kc=0; kc<16; ++kc){
    const int cur = kc & 1, nxt = cur ^ 1;
    if (kc < 15){
#pragma unroll
      for (int g=0; g<NG; ++g)
#pragma unroll
        for (int nn=0; nn<2; ++nn)
          b[nxt][g][nn] = wbase8[((((kc+1)*4) + (N0+nn))*4 + g)*64];
    }
    int ko = kc*32 + lhi*8;
    short8 a0 = *(const short8*)&As[ llo     *512 + (ko ^ sw)];
    short8 a1 = *(const short8*)&As[(llo+16)*512 + (ko ^ sw)];
#pragma unroll
    for (int g=0; g<NG; ++g)
#pragma unroll
      for (int nn=0; nn<2; ++nn){
        acc[0][g][nn] = __builtin_amdgcn_mfma_f32_16x16x32_bf16(a0, b[cur][g][nn], acc[0][g][nn], 0, 0, 0);
        acc[1][g][nn] = __builtin_amdgcn_mfma_f32_16x16x32_bf16(a1, b[cur][g][nn], acc[1][g][nn], 0, 0, 0);
      }
  }
}

template<int NG, int N0>
__device__ __forceinline__ void cell_update(
    const f32x4 (&acc)[2][NG][2], const float (&yv)[2][4],
    const float (&bias2)[4][4], const float (&wihv)[4][4], const float (&v1v)[4],
    float (&cst)[2][4][4], float (&part)[2][4])
{
#pragma unroll
  for (int m=0;m<2;++m)
#pragma unroll
    for (int nn=0;nn<2;++nn){
      int gn = N0 + nn;
#pragma unroll
      for (int r=0;r<4;++r){
        float gi = acc[m][0][nn][r] + fmaf(yv[m][r], wihv[0][gn], bias2[0][gn]);
        float gf = acc[m][1][nn][r] + fmaf(yv[m][r], wihv[1][gn], bias2[1][gn]);
        float gg = acc[m][2][nn][r] + fmaf(yv[m][r], wihv[2][gn], bias2[2][gn]);
        float c  = sigf(gf)*cst[m][gn][r] + sigf(gi)*tanh_(gg);
        cst[m][gn][r] = c;
        if (NG == 4){
          float go = acc[m][3][nn][r] + fmaf(yv[m][r], wihv[3][gn], bias2[3][gn]);
          part[m][r] += sigf(go)*tanh_(c)*v1v[gn];
        }
      }
    }
}

template<int NG>
__device__ __forceinline__ void step_gemm(
    const unsigned short* As, const short8* __restrict__ wbase8,
    int llo, int lhi, const float (&yv)[2][4],
    const float (&bias2)[4][4], const float (&wihv)[4][4], const float (&v1v)[4],
    float (&cst)[2][4][4], float (&part)[2][4])
{
  {
    f32x4 acc[2][NG][2];
#pragma unroll
    for (int m=0;m<2;++m)
#pragma unroll
      for (int g=0;g<NG;++g)
#pragma unroll
        for (int nn=0;nn<2;++nn) acc[m][g][nn] = (f32x4){0.f,0.f,0.f,0.f};
    gemm_pass<NG,0>(As, wbase8, llo, lhi, acc);
    cell_update<NG,0>(acc, yv, bias2, wihv, v1v, cst, part);
  }
  {
    f32x4 acc[2][NG][2];
#pragma unroll
    for (int m=0;m<2;++m)
#pragma unroll
      for (int g=0;g<NG;++g)
#pragma unroll
        for (int nn=0;nn<2;++nn) acc[m][g][nn] = (f32x4){0.f,0.f,0.f,0.f};
    gemm_pass<NG,2>(As, wbase8, llo, lhi, acc);
    cell_update<NG,2>(acc, yv, bias2, wihv, v1v, cst, part);
  }
}

// ---- K1: fused gates GEMM + LSTM scan + d.v1 contribution ------------------
__global__ __launch_bounds__(512, 2) void k_main(
    const float* __restrict__ h, const float* __restrict__ y,
    const float* __restrict__ Wih, const float* __restrict__ bih,
    const float* __restrict__ bhh,
    const unsigned short* __restrict__ wpack_us, const float* __restrict__ v1,
    float* __restrict__ out)
{
  __shared__ __align__(16) unsigned short As[BT*512];
  __shared__ float ys[BT*T_STEPS];
  const short8* wp8 = (const short8*)wpack_us;
  int tid = threadIdx.x;
  int w = tid >> 6, lane = tid & 63, lhi = lane >> 4, llo = lane & 15;
  int b0 = blockIdx.x * BT;

  // per-wave contiguous W base: + w*16384 short8-chunks, + lane
  const short8* wbase8 = wp8 + (size_t)w*16384 + lane;

  float bias2[4][4], wihv[4][4], v1v[4];
#pragma unroll
  for (int g=0;g<4;++g)
#pragma unroll
    for (int n=0;n<4;++n){
      int col = g*512 + (w*4+n)*16 + llo;
      bias2[g][n] = bih[col] + bhh[col];
      wihv[g][n]  = Wih[col];
    }
#pragma unroll
  for (int n=0;n<4;++n) v1v[n] = v1[(w*4+n)*16 + llo];

  float cst[2][4][4];
  float part[2][4];
#pragma unroll
  for (int m=0;m<2;++m){
#pragma unroll
    for (int n=0;n<4;++n)
#pragma unroll
      for (int r=0;r<4;++r) cst[m][n][r] = 0.f;
#pragma unroll
    for (int r=0;r<4;++r) part[m][r] = 0.f;
  }

  // y tile: coalesced one-shot load
  if (tid < BT*T_STEPS) ys[tid] = y[(size_t)b0*T_STEPS + tid];

  // T14: issue h loads for t=0
  float4 hx[4][2];
#pragma unroll
  for (int i=0;i<4;++i){
    int cid = tid + i*512;
    int row = cid >> 6, ko = (cid & 63)*8;
    const float* hp = h + ((size_t)(b0+row)*T_STEPS + 0)*512 + ko;
    hx[i][0] = *(const float4*)hp;
    hx[i][1] = *(const float4*)(hp+4);
  }

#pragma unroll 1
  for (int t=0; t<T_STEPS; ++t){
    // convert + write LDS (previous iteration's tail barrier protects As)
#pragma unroll
    for (int i=0;i<4;++i){
      int cid = tid + i*512;
      int row = cid >> 6, ko = (cid & 63)*8;
      uint4 pkv;
      pkv.x = pk2(hx[i][0].x,hx[i][0].y); pkv.y = pk2(hx[i][0].z,hx[i][0].w);
      pkv.z = pk2(hx[i][1].x,hx[i][1].y); pkv.w = pk2(hx[i][1].z,hx[i][1].w);
      *(uint4*)&As[row*512 + (ko ^ ((row&7)<<3))] = pkv;
    }
    __syncthreads();   // As ready

    // issue next step's h loads -> overlap with GEMM (T14)
    if (t < T_STEPS-1){
#pragma unroll
      for (int i=0;i<4;++i){
        int cid = tid + i*512;
        int row = cid >> 6, ko = (cid & 63)*8;
        const float* hp = h + ((size_t)(b0+row)*T_STEPS + (t+1))*512 + ko;
        hx[i][0] = *(const float4*)hp;
        hx[i][1] = *(const float4*)(hp+4);
      }
    }

    float yv[2][4];
#pragma unroll
    for (int m=0;m<2;++m)
#pragma unroll
      for (int r=0;r<4;++r)
        yv[m][r] = ys[(m*16 + lhi*4 + r)*T_STEPS + t];

    const short8* wb = wbase8;   // constant offsets inside
    if (t == T_STEPS-1)
      step_gemm<4>(As, wb, llo, lhi, yv, bias2, wihv, v1v, cst, part);
    else
      step_gemm<3>(As, wb, llo, lhi, yv, bias2, wihv, v1v, cst, part);

    __syncthreads();   // all waves done reading As before next overwrite
  }

#pragma unroll
  for (int m=0;m<2;++m)
#pragma unroll
    for (int r=0;r<4;++r){
      float val = part[m][r];
      val += __shfl_xor(val, 1);
      val += __shfl_xor(val, 2);
      val += __shfl_xor(val, 4);
      val += __shfl_xor(val, 8);
      if (llo == 0) atomicAdd(&out[b0 + m*16 + lhi*4 + r], val);
    }
}

extern "C" void kernel_launch(void* const* d_in, const int* in_sizes, int n_in,
                              void* d_out, int out_size, void* d_ws, size_t ws_size,
                              hipStream_t stream){
  (void)in_sizes; (void)n_in; (void)out_size; (void)ws_size;
  const float* h    = (const float*)d_in[0];
  const float* y    = (const float*)d_in[1];
  // d_in[2..7] = attention weights: mathematically dead (softmax over size-1 dim == 1)
  const float* Wih  = (const float*)d_in[8];
  const float* Whh  = (const float*)d_in[9];
  const float* bih  = (const float*)d_in[10];
  const float* bhh  = (const float*)d_in[11];
  const float* fc1w = (const float*)d_in[12];
  const float* fc1b = (const float*)d_in[13];
  const float* fc2w = (const float*)d_in[14];
  const float* fc2b = (const float*)d_in[15];
  float* out = (float*)d_out;

  unsigned short* wpack = (unsigned short*)d_ws;
  float* vbuf  = (float*)((char*)d_ws + WPACK_BYTES);
  float* bias0 = vbuf + 1024;

  k_pack<<<512, 256, 0, stream>>>(Whh, wpack);
  k_v<<<17, 256, 0, stream>>>(fc1w, fc1b, fc2w, fc2b, vbuf, bias0);
  k_init<<<128, 512, 0, stream>>>(h, vbuf, bias0, out);
  k_main<<<256, 512, 0, stream>>>(h, y, Wih, bih, bhh, wpack, vbuf, out);
}

// Round 4
// 994.042 us; speedup vs baseline: 1.1658x; 1.1658x over previous
//
#include <hip/hip_runtime.h>
#include <stdint.h>

typedef __attribute__((ext_vector_type(8))) short short8;
typedef __attribute__((ext_vector_type(4))) float f32x4;
typedef unsigned short ushort_t;

#define T_STEPS 10
#define BT 64
#define WPACK_BYTES (2048*1024)                 // 2048 chunks x 1 KiB
#define VBUF_OFF  WPACK_BYTES
#define HBF_OFF   (WPACK_BYTES + 8192)
#define H_ELEMS   (8192ull*T_STEPS*512)
#define HBF_BYTES (H_ELEMS*2)

typedef const __attribute__((address_space(1))) void gas_void;
typedef __attribute__((address_space(3))) void las_void;

__device__ __forceinline__ void gld_lds16(const void* g, void* l){
  __builtin_amdgcn_global_load_lds((gas_void*)g, (las_void*)l, 16, 0, 0);
}

__device__ __forceinline__ unsigned int pk2(float x, float y){
  unsigned int bx = __float_as_uint(x), by = __float_as_uint(y);
  bx = (bx + 0x7FFFu + ((bx>>16)&1u)) >> 16;     // RNE fp32->bf16
  by = (by + 0x7FFFu + ((by>>16)&1u)) >> 16;
  return bx | (by<<16);
}
__device__ __forceinline__ float sigf(float x){ return 1.f/(1.f + __expf(-x)); }
__device__ __forceinline__ float tanh_(float x){
  x = fminf(fmaxf(x, -15.f), 15.f);
  float e = __expf(2.f*x);
  return (e - 1.f)/(e + 1.f);
}

// ---- K0a: pack W_hh [2048][512] fp32 -> bf16, per-wave-contiguous chunks ---
// chunk = (((js*4 + w)*4 + jt)*16 + kc)*4 + g ; in-chunk lane = khi*16 + jl
__global__ __launch_bounds__(256) void k_pack(const float* __restrict__ Whh,
                                              ushort_t* __restrict__ wp){
  int id  = blockIdx.x*256 + threadIdx.x;   // 0..131071
  int row = id >> 6;                        // gate-col 0..2047
  int ko  = (id & 63) * 8;                  // k offset 0..504
  const float* p = Whh + row*512 + ko;
  float4 a = *(const float4*)p, b = *(const float4*)(p+4);
  uint4 v;
  v.x = pk2(a.x,a.y); v.y = pk2(a.z,a.w);
  v.z = pk2(b.x,b.y); v.w = pk2(b.z,b.w);
  int g = row >> 9, j = row & 511;
  int js = j >> 8, w = (j >> 6) & 3, jt = (j >> 4) & 3, jl = j & 15;
  int kc = ko >> 5, khi = (ko >> 3) & 3, lane = khi*16 + jl;
  int chunk = ((((js*4 + w)*4 + jt)*16 + kc)*4) + g;
  *(uint4*)(wp + chunk*512 + lane*8) = v;
}

// ---- K0b: v[j] = sum_h fc2[h]*fc1[h][j]; bias0 = fc2.fc1_b + fc2_b --------
__global__ __launch_bounds__(256) void k_v(const float* __restrict__ fc1w,
                                           const float* __restrict__ fc1b,
                                           const float* __restrict__ fc2w,
                                           const float* __restrict__ fc2b,
                                           float* __restrict__ vout,
                                           float* __restrict__ bias0){
  __shared__ float red[4][64];
  int tid = threadIdx.x;
  if (blockIdx.x < 16){
    int j  = blockIdx.x*64 + (tid & 63);
    int hc = tid >> 6;
    float s = 0.f;
    for (int hh = hc*128; hh < hc*128 + 128; ++hh)
      s += fc2w[hh] * fc1w[hh*1024 + j];
    red[hc][tid & 63] = s;
    __syncthreads();
    if (tid < 64)
      vout[blockIdx.x*64 + tid] = red[0][tid]+red[1][tid]+red[2][tid]+red[3][tid];
  } else {
    if (tid < 64){
      float s = 0.f;
      for (int i = 0; i < 8; ++i){ int hh = i*64 + tid; s += fc2w[hh]*fc1b[hh]; }
      for (int m = 32; m; m >>= 1) s += __shfl_xor(s, m);
      if (tid == 0) *bias0 = s + fc2b[0];
    }
  }
}

// ---- K2: out[b] = h[b,9,:].v2 + bias0 (overwrite -> deterministic init) ---
__global__ __launch_bounds__(512) void k_init(const float* __restrict__ h,
                                              const float* __restrict__ v,
                                              const float* __restrict__ bias0,
                                              float* __restrict__ out){
  int w = threadIdx.x >> 6, lane = threadIdx.x & 63;
  float b0v = *bias0;
  const float* v2 = v + 512;
  for (int r = 0; r < 8; ++r){
    int b = blockIdx.x*64 + w*8 + r;
    const float* hp = h + ((size_t)b*T_STEPS + 9)*512 + lane*8;
    float4 x0 = *(const float4*)hp, x1 = *(const float4*)(hp+4);
    const float* vp = v2 + lane*8;
    float4 w0 = *(const float4*)vp, w1 = *(const float4*)(vp+4);
    float s = x0.x*w0.x + x0.y*w0.y + x0.z*w0.z + x0.w*w0.w
            + x1.x*w1.x + x1.y*w1.y + x1.z*w1.z + x1.w*w1.w;
    for (int m = 32; m; m >>= 1) s += __shfl_xor(s, m);
    if (lane == 0) out[b] = s + b0v;
  }
}

// ---- K0c: h fp32 -> bf16 (linear), 16 elems/thread ------------------------
// grid MUST be H_ELEMS/16/256 = 10240 blocks (R3 bug: was 2x -> OOB fault)
__global__ __launch_bounds__(256) void k_prep(const float* __restrict__ h,
                                              ushort_t* __restrict__ hbf){
  size_t id = (size_t)blockIdx.x*256 + threadIdx.x;
  if (id*16 >= H_ELEMS) return;
  const float* p = h + id*16;
  float4 a = *(const float4*)p,     b = *(const float4*)(p+4);
  float4 c = *(const float4*)(p+8), d = *(const float4*)(p+12);
  uint4 lo, hi;
  lo.x = pk2(a.x,a.y); lo.y = pk2(a.z,a.w); lo.z = pk2(b.x,b.y); lo.w = pk2(b.z,b.w);
  hi.x = pk2(c.x,c.y); hi.y = pk2(c.z,c.w); hi.z = pk2(d.x,d.y); hi.w = pk2(d.z,d.w);
  uint4* q = (uint4*)(hbf + id*16);
  q[0] = lo; q[1] = hi;
}

// ---- staging ---------------------------------------------------------------
__device__ __forceinline__ void stage_async(ushort_t* dst, const ushort_t* hbf,
                                            int b0, int t, int w, int lane){
#pragma unroll
  for (int i = 0; i < 16; ++i){
    int row = i*4 + w;
    const ushort_t* src = hbf + ((size_t)(b0 + row)*T_STEPS + t)*512
                        + ((lane ^ (row & 7)) << 3);      // pre-swizzled source
    gld_lds16(src, dst + row*512);                        // HW: base + lane*16
  }
}

__device__ __forceinline__ void stage_sync(ushort_t* dst, const float* h,
                                           int b0, int t, int tid){
  int row = tid >> 2, sub = tid & 3;
  const float* hp = h + ((size_t)(b0 + row)*T_STEPS + t)*512;
#pragma unroll
  for (int i = 0; i < 16; ++i){
    int q = sub*16 + i;
    const float* p = hp + q*8;
    float4 x0 = *(const float4*)p, x1 = *(const float4*)(p+4);
    uint4 pk;
    pk.x = pk2(x0.x,x0.y); pk.y = pk2(x0.z,x0.w);
    pk.z = pk2(x1.x,x1.y); pk.w = pk2(x1.z,x1.w);
    *(uint4*)&dst[row*512 + ((q ^ (row & 7)) << 3)] = pk;
  }
}

// ---- one jt-pass: K=512 GEMM (nn=2 j-tiles) + fused cell update ------------
template<int NG, int JP>
__device__ __forceinline__ void pass(
    const ushort_t* Ac, const short8* __restrict__ wslice,
    int llo, int lhi, const float (&yv)[4][4],
    const float (&bias2)[4][4], const float (&wihv)[4][4], const float (&v1v)[4],
    float (&cst)[4][4][4], float (&part)[4][4])
{
  constexpr int RING = (NG == 3) ? 4 : 2;      // prefetch distance RING-1
  f32x4 acc[4][NG][2];
#pragma unroll
  for (int m=0;m<4;++m)
#pragma unroll
    for (int g=0;g<NG;++g)
#pragma unroll
      for (int n=0;n<2;++n) acc[m][g][n] = (f32x4){0.f,0.f,0.f,0.f};

  short8 bb[RING][NG][2];
#pragma unroll
  for (int p=0; p<RING-1; ++p)
#pragma unroll
    for (int g=0; g<NG; ++g)
#pragma unroll
      for (int n=0; n<2; ++n)
        bb[p][g][n] = wslice[(((JP*2+n)*16 + p)*4 + g)*64];

#pragma unroll
  for (int kc=0; kc<16; ++kc){
    if (kc < 16-(RING-1)){
#pragma unroll
      for (int g=0; g<NG; ++g)
#pragma unroll
        for (int n=0; n<2; ++n)
          bb[(kc+RING-1)&(RING-1)][g][n] =
              wslice[(((JP*2+n)*16 + kc+RING-1)*4 + g)*64];
    }
    short8 af[4];
#pragma unroll
    for (int m=0; m<4; ++m){
      int q = kc*4 + lhi;
      af[m] = *(const short8*)&Ac[(m*16 + llo)*512 + ((q ^ (llo&7))<<3)];
    }
#pragma unroll
    for (int g=0; g<NG; ++g)
#pragma unroll
      for (int n=0; n<2; ++n)
#pragma unroll
        for (int m=0; m<4; ++m)
          acc[m][g][n] = __builtin_amdgcn_mfma_f32_16x16x32_bf16(
              af[m], bb[kc&(RING-1)][g][n], acc[m][g][n], 0, 0, 0);
  }

#pragma unroll
  for (int m=0;m<4;++m)
#pragma unroll
    for (int n=0;n<2;++n){
      const int jt = JP*2 + n;
#pragma unroll
      for (int r=0;r<4;++r){
        float gi = acc[m][0][n][r] + fmaf(yv[m][r], wihv[0][jt], bias2[0][jt]);
        float gf = acc[m][1][n][r] + fmaf(yv[m][r], wihv[1][jt], bias2[1][jt]);
        float gg = acc[m][2][n][r] + fmaf(yv[m][r], wihv[2][jt], bias2[2][jt]);
        float c  = sigf(gf)*cst[m][jt][r] + sigf(gi)*tanh_(gg);
        cst[m][jt][r] = c;
        if (NG == 4){
          float go = acc[m][3][n][r] + fmaf(yv[m][r], wihv[3][jt], bias2[3][jt]);
          part[m][r] += sigf(go)*tanh_(c)*v1v[jt];
        }
      }
    }
}

// ---- K1: fused gates GEMM + LSTM scan + d.v1 contribution ------------------
template<bool PREP>
__global__ __launch_bounds__(256, 1) __attribute__((amdgpu_waves_per_eu(1, 1)))
void k_main(const float* __restrict__ h, const ushort_t* __restrict__ hbf,
            const float* __restrict__ y,
            const float* __restrict__ Wih, const float* __restrict__ bih,
            const float* __restrict__ bhh,
            const ushort_t* __restrict__ wpack_us, const float* __restrict__ v1,
            float* __restrict__ out)
{
  __shared__ __align__(16) ushort_t As[2][BT*512];   // 128 KiB
  int tid = threadIdx.x;
  int w = tid >> 6, lane = tid & 63, lhi = lane >> 4, llo = lane & 15;
  int bid = blockIdx.x;
  int tile = (bid & 7) | ((bid >> 4) << 3);     // sibling js-blocks share XCD
  int js   = (bid >> 3) & 1;
  int b0 = tile * BT;

  const short8* wslice = (const short8*)wpack_us + ((size_t)(js*4 + w))*16384 + lane;

  float bias2[4][4], wihv[4][4], v1v[4];
  int jcb = js*256 + w*64 + llo;
#pragma unroll
  for (int g=0; g<4; ++g)
#pragma unroll
    for (int jt=0; jt<4; ++jt){
      int col = g*512 + jcb + jt*16;
      bias2[g][jt] = bih[col] + bhh[col];
      wihv[g][jt]  = Wih[col];
    }
#pragma unroll
  for (int jt=0; jt<4; ++jt) v1v[jt] = v1[jcb + jt*16];

  float cst[4][4][4], part[4][4];
#pragma unroll
  for (int m=0;m<4;++m){
#pragma unroll
    for (int jt=0;jt<4;++jt)
#pragma unroll
      for (int r=0;r<4;++r) cst[m][jt][r] = 0.f;
#pragma unroll
    for (int r=0;r<4;++r) part[m][r] = 0.f;
  }

  if constexpr (PREP) stage_async(&As[0][0], hbf, b0, 0, w, lane);
  else                stage_sync (&As[0][0], h,   b0, 0, tid);
  __syncthreads();

#pragma unroll 1
  for (int t=0; t<T_STEPS; ++t){
    const ushort_t* Ac = PREP ? &As[t & 1][0] : &As[0][0];
    if constexpr (PREP){
      if (t < T_STEPS-1) stage_async(&As[(t+1)&1][0], hbf, b0, t+1, w, lane);
    }
    float yv[4][4];
#pragma unroll
    for (int m=0;m<4;++m)
#pragma unroll
      for (int r=0;r<4;++r)
        yv[m][r] = y[(size_t)(b0 + m*16 + lhi*4 + r)*T_STEPS + t];

    if (t < T_STEPS-1){
      pass<3,0>(Ac, wslice, llo, lhi, yv, bias2, wihv, v1v, cst, part);
      pass<3,1>(Ac, wslice, llo, lhi, yv, bias2, wihv, v1v, cst, part);
    } else {
      pass<4,0>(Ac, wslice, llo, lhi, yv, bias2, wihv, v1v, cst, part);
      pass<4,1>(Ac, wslice, llo, lhi, yv, bias2, wihv, v1v, cst, part);
    }
    __syncthreads();
    if constexpr (!PREP){
      if (t < T_STEPS-1){
        stage_sync(&As[0][0], h, b0, t+1, tid);
        __syncthreads();
      }
    }
  }

#pragma unroll
  for (int m=0;m<4;++m)
#pragma unroll
    for (int r=0;r<4;++r){
      float val = part[m][r];
      val += __shfl_xor(val, 1);
      val += __shfl_xor(val, 2);
      val += __shfl_xor(val, 4);
      val += __shfl_xor(val, 8);
      if (llo == 0) atomicAdd(&out[b0 + m*16 + lhi*4 + r], val);
    }
}

extern "C" void kernel_launch(void* const* d_in, const int* in_sizes, int n_in,
                              void* d_out, int out_size, void* d_ws, size_t ws_size,
                              hipStream_t stream){
  (void)in_sizes; (void)n_in; (void)out_size;
  const float* h    = (const float*)d_in[0];
  const float* y    = (const float*)d_in[1];
  // d_in[2..7] = attention weights: mathematically dead (softmax over size-1 dim == 1)
  const float* Wih  = (const float*)d_in[8];
  const float* Whh  = (const float*)d_in[9];
  const float* bih  = (const float*)d_in[10];
  const float* bhh  = (const float*)d_in[11];
  const float* fc1w = (const float*)d_in[12];
  const float* fc1b = (const float*)d_in[13];
  const float* fc2w = (const float*)d_in[14];
  const float* fc2b = (const float*)d_in[15];
  float* out = (float*)d_out;

  ushort_t* wpack = (ushort_t*)d_ws;
  float* vbuf  = (float*)((char*)d_ws + VBUF_OFF);
  float* bias0 = vbuf + 1024;
  ushort_t* hbf = (ushort_t*)((char*)d_ws + HBF_OFF);
  bool prep = ws_size >= (size_t)HBF_OFF + HBF_BYTES;

  k_pack<<<512, 256, 0, stream>>>(Whh, wpack);
  k_v<<<17, 256, 0, stream>>>(fc1w, fc1b, fc2w, fc2b, vbuf, bias0);
  if (prep){
    int prep_blocks = (int)(H_ELEMS / 16 / 256);   // = 10240, exact
    k_prep<<<prep_blocks, 256, 0, stream>>>(h, hbf);
  }
  k_init<<<128, 512, 0, stream>>>(h, vbuf, bias0, out);
  if (prep)
    k_main<true ><<<256, 256, 0, stream>>>(h, hbf, y, Wih, bih, bhh, wpack, vbuf, out);
  else
    k_main<false><<<256, 256, 0, stream>>>(h, hbf, y, Wih, bih, bhh, wpack, vbuf, out);
}